// Round 1
// baseline (2826.785 us; speedup 1.0000x reference)
//
#include <hip/hip_runtime.h>
#include <cstddef>

#define BB 4
#define SS 2048
#define HH 1024
#define NH 16
#define HD 64

// ---------------- fp32 SGEMM: C[M,N] = A[M,K] @ W[N,K]^T (+ bias[N]) ----------------
// 128x128 tile, BK=16, 256 threads, 8x8 micro-tile per thread.
template<bool HAS_BIAS>
__global__ __launch_bounds__(256)
void sgemm_bt(const float* __restrict__ A, const float* __restrict__ W,
              const float* __restrict__ bias, float* __restrict__ C,
              int M, int N, int K)
{
    __shared__ float As[16][132];   // [k][m], stride 132 floats = 528B (16B aligned)
    __shared__ float Bs[16][132];   // [k][n]
    const int t  = threadIdx.x;
    const int m0 = blockIdx.y * 128;
    const int n0 = blockIdx.x * 128;
    const int tx = t & 15, ty = t >> 4;
    const int lrow = t >> 2;          // 0..63
    const int lk4  = (t & 3) << 2;    // 0,4,8,12

    float acc[8][8];
#pragma unroll
    for (int i = 0; i < 8; ++i)
#pragma unroll
        for (int j = 0; j < 8; ++j) acc[i][j] = 0.f;

    for (int kb = 0; kb < K; kb += 16) {
#pragma unroll
        for (int r = 0; r < 2; ++r) {
            const int row = lrow + (r << 6);
            const float4 av = *(const float4*)&A[(size_t)(m0 + row) * K + kb + lk4];
            As[lk4 + 0][row] = av.x; As[lk4 + 1][row] = av.y;
            As[lk4 + 2][row] = av.z; As[lk4 + 3][row] = av.w;
            const float4 wv = *(const float4*)&W[(size_t)(n0 + row) * K + kb + lk4];
            Bs[lk4 + 0][row] = wv.x; Bs[lk4 + 1][row] = wv.y;
            Bs[lk4 + 2][row] = wv.z; Bs[lk4 + 3][row] = wv.w;
        }
        __syncthreads();
#pragma unroll
        for (int k = 0; k < 16; ++k) {
            float a[8], b[8];
            *(float4*)&a[0] = *(const float4*)&As[k][ty * 8];
            *(float4*)&a[4] = *(const float4*)&As[k][ty * 8 + 4];
            *(float4*)&b[0] = *(const float4*)&Bs[k][tx * 8];
            *(float4*)&b[4] = *(const float4*)&Bs[k][tx * 8 + 4];
#pragma unroll
            for (int i = 0; i < 8; ++i)
#pragma unroll
                for (int j = 0; j < 8; ++j)
                    acc[i][j] = fmaf(a[i], b[j], acc[i][j]);
        }
        __syncthreads();
    }

#pragma unroll
    for (int i = 0; i < 8; ++i) {
        const int m = m0 + ty * 8 + i;
#pragma unroll
        for (int j4 = 0; j4 < 8; j4 += 4) {
            float4 v;
            v.x = acc[i][j4 + 0]; v.y = acc[i][j4 + 1];
            v.z = acc[i][j4 + 2]; v.w = acc[i][j4 + 3];
            if (HAS_BIAS) {
                v.x += bias[n0 + tx * 8 + j4 + 0];
                v.y += bias[n0 + tx * 8 + j4 + 1];
                v.z += bias[n0 + tx * 8 + j4 + 2];
                v.w += bias[n0 + tx * 8 + j4 + 3];
            }
            *(float4*)&C[(size_t)m * N + n0 + tx * 8 + j4] = v;
        }
    }
}

// ---------------- fp32 flash-style masked attention ----------------
// Block: 256 threads = 16 query rows x 16 lanes. Per (b,h), 16-query tile.
// Key/value tiles of 64 staged in LDS. Online softmax, 16-lane shuffle reductions.
// Allowed(q,j) := mask[b,q]==0 && mask[b,j]==0 && q!=j. Rows w/o allowed keys -> 0.
__global__ __launch_bounds__(256)
void attn_fused(const float* __restrict__ Qg, const float* __restrict__ Kg,
                const float* __restrict__ Vg, const int* __restrict__ mask,
                float* __restrict__ Og)
{
    __shared__ float qs[16][68];
    __shared__ float ks[64][68];
    __shared__ float vs[64][68];
    __shared__ float wsm[16][68];
    __shared__ int   ms[64];

    const int t  = threadIdx.x;
    const int qi = t >> 4;          // query row in tile (0..15)
    const int u  = t & 15;          // lane within row group
    const int bh = blockIdx.y;
    const int b  = bh >> 4;
    const int h  = bh & 15;
    const int q0 = blockIdx.x << 4;
    const int qg = q0 + qi;
    const size_t base = ((size_t)b * SS) * HH + (size_t)h * HD;

    // load Q tile (row qi, 4 floats per lane)
    *(float4*)&qs[qi][u << 2] = *(const float4*)&Qg[base + (size_t)qg * HH + (u << 2)];
    const int mq = mask[b * SS + qg];

    float m_run = -1e30f, l_run = 0.f;
    float4 o4 = make_float4(0.f, 0.f, 0.f, 0.f);

    const int lrow = t >> 2;           // 0..63
    const int lc   = (t & 3) << 4;     // 0,16,32,48

    for (int j0 = 0; j0 < SS; j0 += 64) {
        __syncthreads();   // previous tile fully consumed
        const float* kp = &Kg[base + (size_t)(j0 + lrow) * HH + lc];
        const float* vp = &Vg[base + (size_t)(j0 + lrow) * HH + lc];
#pragma unroll
        for (int c = 0; c < 4; ++c) {
            *(float4*)&ks[lrow][lc + (c << 2)] = *(const float4*)&kp[c << 2];
            *(float4*)&vs[lrow][lc + (c << 2)] = *(const float4*)&vp[c << 2];
        }
        if (t < 64) ms[t] = mask[b * SS + j0 + t];
        __syncthreads();

        // scores: each thread computes 4 dots (j = u, u+16, u+32, u+48)
        float s[4] = {0.f, 0.f, 0.f, 0.f};
#pragma unroll
        for (int d0 = 0; d0 < 64; d0 += 4) {
            const float4 qv = *(const float4*)&qs[qi][d0];
#pragma unroll
            for (int r = 0; r < 4; ++r) {
                const float4 kv = *(const float4*)&ks[u + (r << 4)][d0];
                s[r] = fmaf(qv.x, kv.x, fmaf(qv.y, kv.y,
                        fmaf(qv.z, kv.z, fmaf(qv.w, kv.w, s[r]))));
            }
        }
#pragma unroll
        for (int r = 0; r < 4; ++r) {
            const int j = j0 + u + (r << 4);
            const bool ok = (ms[u + (r << 4)] == 0) && (j != qg);
            s[r] = ok ? s[r] * 0.125f : -1e30f;
        }

        // row max over 64 entries (4 per thread x 16 lanes)
        float mt = fmaxf(fmaxf(s[0], s[1]), fmaxf(s[2], s[3]));
#pragma unroll
        for (int off = 8; off; off >>= 1)
            mt = fmaxf(mt, __shfl_xor(mt, off, 16));

        const float m_new = fmaxf(m_run, mt);
        const float corr  = __expf(m_run - m_new);   // exp(0)=1 when both -1e30
        float w[4], rs = 0.f;
#pragma unroll
        for (int r = 0; r < 4; ++r) {
            w[r] = (s[r] < -1e29f) ? 0.f : __expf(s[r] - m_new);
            rs += w[r];
        }
#pragma unroll
        for (int off = 8; off; off >>= 1)
            rs += __shfl_xor(rs, off, 16);

        l_run = l_run * corr + rs;
        m_run = m_new;
        o4.x *= corr; o4.y *= corr; o4.z *= corr; o4.w *= corr;

#pragma unroll
        for (int r = 0; r < 4; ++r) wsm[qi][u + (r << 4)] = w[r];
        __syncthreads();

        // PV: o[d] += sum_j w[j] * V[j][d]; skip key columns whose w==0 wave-wide
        for (int jb = 0; jb < 16; ++jb) {
            const float4 wv = *(const float4*)&wsm[qi][jb << 2];
            const float wArr[4] = {wv.x, wv.y, wv.z, wv.w};
#pragma unroll
            for (int c2 = 0; c2 < 4; ++c2) {
                const float wj = wArr[c2];
                if (wj != 0.f) {   // masked j -> all lanes 0 -> execz skip
                    const float4 vv = *(const float4*)&vs[(jb << 2) + c2][u << 2];
                    o4.x = fmaf(wj, vv.x, o4.x);
                    o4.y = fmaf(wj, vv.y, o4.y);
                    o4.z = fmaf(wj, vv.z, o4.z);
                    o4.w = fmaf(wj, vv.w, o4.w);
                }
            }
        }
    }

    const float inv = (mq == 0 && l_run > 0.f) ? 1.0f / l_run : 0.f;
    o4.x *= inv; o4.y *= inv; o4.z *= inv; o4.w *= inv;
    *(float4*)&Og[base + (size_t)qg * HH + (u << 2)] = o4;
}

// ---------------- launch ----------------
extern "C" void kernel_launch(void* const* d_in, const int* in_sizes, int n_in,
                              void* d_out, int out_size, void* d_ws, size_t ws_size,
                              hipStream_t stream)
{
    (void)in_sizes; (void)n_in; (void)out_size; (void)ws_size;

    const float* x  = (const float*)d_in[0];
    const int*   mk = (const int*)d_in[1];
    const float* Wq = (const float*)d_in[2];
    const float* bq = (const float*)d_in[3];
    const float* Wk = (const float*)d_in[4];
    const float* bk = (const float*)d_in[5];
    const float* Wv = (const float*)d_in[6];
    const float* bv = (const float*)d_in[7];
    const float* Wc = (const float*)d_in[8];
    float* out = (float*)d_out;

    const int M = BB * SS;  // 8192
    float* Qb = (float*)d_ws;
    float* Kb = Qb + (size_t)M * HH;
    float* Vb = Kb + (size_t)M * HH;
    float* Ob = Vb + (size_t)M * HH;

    dim3 gg(HH / 128, M / 128);  // (8, 64)
    sgemm_bt<true><<<gg, 256, 0, stream>>>(x, Wq, bq, Qb, M, HH, HH);
    sgemm_bt<true><<<gg, 256, 0, stream>>>(x, Wk, bk, Kb, M, HH, HH);
    sgemm_bt<true><<<gg, 256, 0, stream>>>(x, Wv, bv, Vb, M, HH, HH);

    dim3 ga(SS / 16, BB * NH);   // (128, 64)
    attn_fused<<<ga, 256, 0, stream>>>(Qb, Kb, Vb, mk, Ob);

    sgemm_bt<false><<<gg, 256, 0, stream>>>(Ob, Wc, nullptr, out, M, HH, HH);
}

// Round 2
// 971.630 us; speedup vs baseline: 2.9093x; 2.9093x over previous
//
#include <hip/hip_runtime.h>
#include <cstddef>

#define BB 4
#define SS 2048
#define HH 1024
#define NH 16
#define HD 64

typedef _Float16 half8 __attribute__((ext_vector_type(8)));
typedef _Float16 half4v __attribute__((ext_vector_type(4)));
typedef float f32x4 __attribute__((ext_vector_type(4)));

// ---------------- fp32 SGEMM: C[M,N] = A[M,K] @ W[N,K]^T (+ bias[N]) ----------------
// 128x128 tile, BK=16, 256 threads, 8x8 micro-tile per thread.
// F16O: write fp16 head-major [bh][s][64] (for Q/K/V); else fp32 row-major.
template<bool HAS_BIAS, bool F16O>
__global__ __launch_bounds__(256)
void sgemm_bt(const float* __restrict__ A, const float* __restrict__ W,
              const float* __restrict__ bias, void* __restrict__ Cout,
              int M, int N, int K)
{
    __shared__ float As[16][132];
    __shared__ float Bs[16][132];
    const int t  = threadIdx.x;
    const int m0 = blockIdx.y * 128;
    const int n0 = blockIdx.x * 128;
    const int tx = t & 15, ty = t >> 4;
    const int lrow = t >> 2;
    const int lk4  = (t & 3) << 2;

    float acc[8][8];
#pragma unroll
    for (int i = 0; i < 8; ++i)
#pragma unroll
        for (int j = 0; j < 8; ++j) acc[i][j] = 0.f;

    for (int kb = 0; kb < K; kb += 16) {
#pragma unroll
        for (int r = 0; r < 2; ++r) {
            const int row = lrow + (r << 6);
            const float4 av = *(const float4*)&A[(size_t)(m0 + row) * K + kb + lk4];
            As[lk4 + 0][row] = av.x; As[lk4 + 1][row] = av.y;
            As[lk4 + 2][row] = av.z; As[lk4 + 3][row] = av.w;
            const float4 wv = *(const float4*)&W[(size_t)(n0 + row) * K + kb + lk4];
            Bs[lk4 + 0][row] = wv.x; Bs[lk4 + 1][row] = wv.y;
            Bs[lk4 + 2][row] = wv.z; Bs[lk4 + 3][row] = wv.w;
        }
        __syncthreads();
#pragma unroll
        for (int k = 0; k < 16; ++k) {
            float a[8], b[8];
            *(float4*)&a[0] = *(const float4*)&As[k][ty * 8];
            *(float4*)&a[4] = *(const float4*)&As[k][ty * 8 + 4];
            *(float4*)&b[0] = *(const float4*)&Bs[k][tx * 8];
            *(float4*)&b[4] = *(const float4*)&Bs[k][tx * 8 + 4];
#pragma unroll
            for (int i = 0; i < 8; ++i)
#pragma unroll
                for (int j = 0; j < 8; ++j)
                    acc[i][j] = fmaf(a[i], b[j], acc[i][j]);
        }
        __syncthreads();
    }

    if constexpr (F16O) {
        _Float16* C16 = (_Float16*)Cout;
#pragma unroll
        for (int i = 0; i < 8; ++i) {
            const int m = m0 + ty * 8 + i;
            const int bI = m >> 11, sI = m & (SS - 1);
            const int n  = n0 + tx * 8;
            const int hI = n >> 6, dI = n & 63;
            _Float16* dst = C16 + (((size_t)(bI * NH + hI) * SS + sI) * HD + dI);
            half4v v0, v1;
#pragma unroll
            for (int j = 0; j < 4; ++j)
                v0[j] = (_Float16)(acc[i][j] + (HAS_BIAS ? bias[n + j] : 0.f));
#pragma unroll
            for (int j = 0; j < 4; ++j)
                v1[j] = (_Float16)(acc[i][4 + j] + (HAS_BIAS ? bias[n + 4 + j] : 0.f));
            *(half4v*)dst       = v0;
            *(half4v*)(dst + 4) = v1;
        }
    } else {
        float* C = (float*)Cout;
#pragma unroll
        for (int i = 0; i < 8; ++i) {
            const int m = m0 + ty * 8 + i;
#pragma unroll
            for (int j4 = 0; j4 < 8; j4 += 4) {
                float4 v;
                v.x = acc[i][j4 + 0]; v.y = acc[i][j4 + 1];
                v.z = acc[i][j4 + 2]; v.w = acc[i][j4 + 3];
                if (HAS_BIAS) {
                    v.x += bias[n0 + tx * 8 + j4 + 0];
                    v.y += bias[n0 + tx * 8 + j4 + 1];
                    v.z += bias[n0 + tx * 8 + j4 + 2];
                    v.w += bias[n0 + tx * 8 + j4 + 3];
                }
                *(float4*)&C[(size_t)m * N + n0 + tx * 8 + j4] = v;
            }
        }
    }
}

// ---------------- V transpose: Vh[bh][s][64] -> Vt[bh][64][2048] ----------------
__global__ __launch_bounds__(256)
void transpose_v(const _Float16* __restrict__ Vh, _Float16* __restrict__ Vt)
{
    __shared__ _Float16 tile[64][72];
    const int t  = threadIdx.x;
    const int bh = blockIdx.y;
    const int s0 = blockIdx.x << 6;
    const int r = t >> 2, c = (t & 3) << 4;
    const _Float16* src = Vh + ((size_t)bh * SS + s0 + r) * HD + c;
    *(half8*)&tile[r][c]     = *(const half8*)src;
    *(half8*)&tile[r][c + 8] = *(const half8*)(src + 8);
    __syncthreads();
    const int d = t >> 2, sc = (t & 3) << 4;
    half8 o0, o1;
#pragma unroll
    for (int i = 0; i < 8; ++i) o0[i] = tile[sc + i][d];
#pragma unroll
    for (int i = 0; i < 8; ++i) o1[i] = tile[sc + 8 + i][d];
    _Float16* dst = Vt + ((size_t)bh * HD + d) * SS + s0 + sc;
    *(half8*)dst       = o0;
    *(half8*)(dst + 8) = o1;
}

// ---------------- fp16-MFMA flash attention ----------------
// Block: 256 thr = 4 waves; wave owns 64 queries (4 subtiles of 16). KV tile = 64.
// S^T = mfma(K, Q): lane&15 = q, key = (lane>>4)*4+reg (+16*tau). Softmax per q:
// in-lane over 16 + shfl_xor 16/32. P stays in registers -> PV B-operand with
// kappa(g,i) = (i>>2)*16 + g*4 + (i&3). O^T accumulated; V^T frags from swizzled LDS.
__global__ __launch_bounds__(256, 2)
void attn_mfma(const _Float16* __restrict__ Qh, const _Float16* __restrict__ Kh,
               const _Float16* __restrict__ Vt, const int* __restrict__ mk,
               float* __restrict__ Og)
{
    __shared__ __align__(16) char ksm[64 * 128];   // K tile, XOR-swizzled rows
    __shared__ __align__(16) char vsm[64 * 128];   // V^T tile, XOR-swizzled rows
    __shared__ float amem[64];                     // additive key mask

    const int t  = threadIdx.x;
    const int w  = t >> 6;
    const int l  = t & 63;
    const int ln = l & 15;
    const int g  = l >> 4;
    const int bh = blockIdx.y;
    const int b  = bh >> 4;
    const int h  = bh & 15;
    const int qbase = (blockIdx.x << 8) + w * 64;

    half8 qf[4][2];
    int   qm[4];
    f32x4 oacc[4][4];
    float mrun[4], lrun[4];
#pragma unroll
    for (int qs = 0; qs < 4; ++qs) {
        const int qg = qbase + qs * 16 + ln;
        const _Float16* qp = Qh + ((size_t)bh * SS + qg) * HD + g * 8;
        qf[qs][0] = *(const half8*)qp;
        qf[qs][1] = *(const half8*)(qp + 32);
        qm[qs] = mk[b * SS + qg];
        mrun[qs] = -1e30f; lrun[qs] = 0.f;
#pragma unroll
        for (int dd = 0; dd < 4; ++dd) oacc[qs][dd] = (f32x4){0.f, 0.f, 0.f, 0.f};
    }

    const int sr   = t >> 2;            // staging row 0..63
    const int scb  = (t & 3) << 5;      // staging byte col 0/32/64/96
    const int swzs = (sr & 7) << 4;

    for (int j0 = 0; j0 < SS; j0 += 64) {
        __syncthreads();
        {
            const char* kg = (const char*)(Kh + ((size_t)bh * SS + j0 + sr) * HD);
            half8 a0 = *(const half8*)(kg + scb);
            half8 a1 = *(const half8*)(kg + scb + 16);
            *(half8*)(ksm + ((sr * 128 + scb)      ^ swzs)) = a0;
            *(half8*)(ksm + ((sr * 128 + scb + 16) ^ swzs)) = a1;
            const char* vg = (const char*)(Vt + ((size_t)bh * HD + sr) * SS + j0);
            half8 b0 = *(const half8*)(vg + scb);
            half8 b1 = *(const half8*)(vg + scb + 16);
            *(half8*)(vsm + ((sr * 128 + scb)      ^ swzs)) = b0;
            *(half8*)(vsm + ((sr * 128 + scb + 16) ^ swzs)) = b1;
            if (t < 64) amem[t] = mk[b * SS + j0 + t] ? -1e30f : 0.f;
        }
        __syncthreads();

        // K fragments (shared across q-subtiles, held in regs)
        half8 kf[4][2];
#pragma unroll
        for (int tau = 0; tau < 4; ++tau) {
            const int row = tau * 16 + ln;
            const int rsw = (row & 7) << 4;
            const int rb  = row * 128;
            kf[tau][0] = *(const half8*)(ksm + ((rb + g * 16)      ^ rsw));
            kf[tau][1] = *(const half8*)(ksm + ((rb + 64 + g * 16) ^ rsw));
        }
        f32x4 amv[4];
#pragma unroll
        for (int tau = 0; tau < 4; ++tau)
            amv[tau] = *(const f32x4*)&amem[tau * 16 + g * 4];

        half8 pf[4][2];
#pragma unroll
        for (int qs = 0; qs < 4; ++qs) {
            f32x4 sa[4];
#pragma unroll
            for (int tau = 0; tau < 4; ++tau) {
                sa[tau] = (f32x4){0.f, 0.f, 0.f, 0.f};
                sa[tau] = __builtin_amdgcn_mfma_f32_16x16x32_f16(kf[tau][0], qf[qs][0], sa[tau], 0, 0, 0);
                sa[tau] = __builtin_amdgcn_mfma_f32_16x16x32_f16(kf[tau][1], qf[qs][1], sa[tau], 0, 0, 0);
            }
            const int rel = (qbase + qs * 16 + ln) - j0;   // diagonal position
            float sv[4][4];
#pragma unroll
            for (int tau = 0; tau < 4; ++tau)
#pragma unroll
                for (int r = 0; r < 4; ++r) {
                    float s = fmaf(sa[tau][r], 0.125f, amv[tau][r]);
                    if (tau * 16 + g * 4 + r == rel) s = -1e30f;
                    sv[tau][r] = s;
                }
            float mt = sv[0][0];
#pragma unroll
            for (int tau = 0; tau < 4; ++tau)
#pragma unroll
                for (int r = 0; r < 4; ++r) mt = fmaxf(mt, sv[tau][r]);
            mt = fmaxf(mt, __shfl_xor(mt, 16));
            mt = fmaxf(mt, __shfl_xor(mt, 32));
            const float mnew = fmaxf(mrun[qs], mt);
            const float corr = __expf(mrun[qs] - mnew);
            mrun[qs] = mnew;
            float wv[4][4], rs = 0.f;
#pragma unroll
            for (int tau = 0; tau < 4; ++tau)
#pragma unroll
                for (int r = 0; r < 4; ++r) {
                    const float e = (sv[tau][r] > -1e29f) ? __expf(sv[tau][r] - mnew) : 0.f;
                    wv[tau][r] = e; rs += e;
                }
            rs += __shfl_xor(rs, 16);
            rs += __shfl_xor(rs, 32);
            lrun[qs] = lrun[qs] * corr + rs;
#pragma unroll
            for (int dd = 0; dd < 4; ++dd) oacc[qs][dd] *= corr;
#pragma unroll
            for (int kk = 0; kk < 2; ++kk) {
                half8 p;
                p[0] = (_Float16)wv[2 * kk][0];     p[1] = (_Float16)wv[2 * kk][1];
                p[2] = (_Float16)wv[2 * kk][2];     p[3] = (_Float16)wv[2 * kk][3];
                p[4] = (_Float16)wv[2 * kk + 1][0]; p[5] = (_Float16)wv[2 * kk + 1][1];
                p[6] = (_Float16)wv[2 * kk + 1][2]; p[7] = (_Float16)wv[2 * kk + 1][3];
                pf[qs][kk] = p;
            }
        }

        // PV: O^T[d][q] += V^T-frag x P-frag  (kappa-matched slot order)
#pragma unroll
        for (int dd = 0; dd < 4; ++dd) {
            const int row = dd * 16 + ln;
            const int rsw = (row & 7) << 4;
            const int rb  = row * 128;
#pragma unroll
            for (int kk = 0; kk < 2; ++kk) {
                half4v a0 = *(const half4v*)(vsm + ((rb + kk * 64 + g * 8)      ^ rsw));
                half4v a1 = *(const half4v*)(vsm + ((rb + kk * 64 + 32 + g * 8) ^ rsw));
                half8 vf;
                vf[0] = a0[0]; vf[1] = a0[1]; vf[2] = a0[2]; vf[3] = a0[3];
                vf[4] = a1[0]; vf[5] = a1[1]; vf[6] = a1[2]; vf[7] = a1[3];
#pragma unroll
                for (int qs = 0; qs < 4; ++qs)
                    oacc[qs][dd] = __builtin_amdgcn_mfma_f32_16x16x32_f16(vf, pf[qs][kk], oacc[qs][dd], 0, 0, 0);
            }
        }
    }

    // epilogue: normalize, zero invalid/empty rows, store O fp32 row-major [b*s][h*64+d]
#pragma unroll
    for (int qs = 0; qs < 4; ++qs) {
        const int qg = qbase + qs * 16 + ln;
        const float inv = (qm[qs] == 0 && lrun[qs] > 0.f) ? 1.f / lrun[qs] : 0.f;
        float* op = Og + ((size_t)(b * SS + qg)) * HH + h * HD + g * 4;
#pragma unroll
        for (int dd = 0; dd < 4; ++dd) {
            f32x4 o = oacc[qs][dd] * inv;
            *(f32x4*)(op + dd * 16) = o;
        }
    }
}

// ---------------- launch ----------------
extern "C" void kernel_launch(void* const* d_in, const int* in_sizes, int n_in,
                              void* d_out, int out_size, void* d_ws, size_t ws_size,
                              hipStream_t stream)
{
    (void)in_sizes; (void)n_in; (void)out_size; (void)ws_size;

    const float* x  = (const float*)d_in[0];
    const int*   mk = (const int*)d_in[1];
    const float* Wq = (const float*)d_in[2];
    const float* bq = (const float*)d_in[3];
    const float* Wk = (const float*)d_in[4];
    const float* bk = (const float*)d_in[5];
    const float* Wv = (const float*)d_in[6];
    const float* bv = (const float*)d_in[7];
    const float* Wc = (const float*)d_in[8];
    float* out = (float*)d_out;

    const int M = BB * SS;                 // 8192
    const size_t NE = (size_t)M * HH;      // elements per tensor
    _Float16* Qh = (_Float16*)d_ws;
    _Float16* Kh = Qh + NE;
    _Float16* Vh = Kh + NE;
    _Float16* Vt = Vh + NE;
    float*    Ob = (float*)(Vt + NE);

    dim3 gg(HH / 128, M / 128);            // (8, 64)
    sgemm_bt<true, true><<<gg, 256, 0, stream>>>(x, Wq, bq, (void*)Qh, M, HH, HH);
    sgemm_bt<true, true><<<gg, 256, 0, stream>>>(x, Wk, bk, (void*)Kh, M, HH, HH);
    sgemm_bt<true, true><<<gg, 256, 0, stream>>>(x, Wv, bv, (void*)Vh, M, HH, HH);

    dim3 gt(SS / 64, BB * NH);             // (32, 64)
    transpose_v<<<gt, 256, 0, stream>>>(Vh, Vt);

    dim3 ga(SS / 256, BB * NH);            // (8, 64)
    attn_mfma<<<ga, 256, 0, stream>>>(Qh, Kh, Vt, mk, Ob);

    sgemm_bt<false, false><<<gg, 256, 0, stream>>>(Ob, Wc, nullptr, (void*)out, M, HH, HH);
}

// Round 3
// 272.357 us; speedup vs baseline: 10.3790x; 3.5675x over previous
//
#include <hip/hip_runtime.h>
#include <cstddef>
#include <cstdint>

#define BB 4
#define SS 2048
#define HH 1024
#define NH 16
#define HD 64

typedef _Float16 half8 __attribute__((ext_vector_type(8)));
typedef _Float16 half4v __attribute__((ext_vector_type(4)));
typedef float f32x4 __attribute__((ext_vector_type(4)));

__device__ __forceinline__ void gload_lds16(const _Float16* g, char* l) {
    __builtin_amdgcn_global_load_lds(
        (const __attribute__((address_space(1))) void*)g,
        (__attribute__((address_space(3))) void*)l, 16, 0, 0);
}

// ---------------- fp32 -> fp16 conversion (8 elems/thread/iter) ----------------
__global__ __launch_bounds__(256)
void cvt_f16(const float* __restrict__ in, _Float16* __restrict__ out, int n8)
{
    int i = blockIdx.x * 256 + threadIdx.x;
    const int stride = gridDim.x * 256;
    for (; i < n8; i += stride) {
        const float4 v0 = ((const float4*)in)[(size_t)i * 2];
        const float4 v1 = ((const float4*)in)[(size_t)i * 2 + 1];
        half8 h;
        h[0] = (_Float16)v0.x; h[1] = (_Float16)v0.y;
        h[2] = (_Float16)v0.z; h[3] = (_Float16)v0.w;
        h[4] = (_Float16)v1.x; h[5] = (_Float16)v1.y;
        h[6] = (_Float16)v1.z; h[7] = (_Float16)v1.w;
        ((half8*)out)[i] = h;
    }
}

// ---------------- fp16 MFMA GEMM core: acc[4][4] for C[m0+128][n0+128] ----------------
// C = A[M,K] @ W[N,K]^T. 4 waves, each 64x64. BK=32 (one 16x16x32 MFMA pair dim).
// LDS tiles [128 rows][64B], XOR-swizzled: phys slot = logical slot ^ ((row>>1)&3),
// realized by pre-swizzling the GLOBAL source (linear global_load_lds dest).
__device__ __forceinline__ void gemm_core(const _Float16* __restrict__ A,
                                          const _Float16* __restrict__ W,
                                          int K, int m0, int n0,
                                          char* As, char* Bs, f32x4 acc[4][4])
{
    const int t = threadIdx.x;
    const int w = t >> 6, lane = t & 63;
    const int ln = lane & 15, g = lane >> 4;
    const int wr = w >> 1, wc = w & 1;

    const int rr0 = w * 16 + (lane >> 2);     // staging rows: call0
    const int rr1 = rr0 + 64;                 // call1
    const int p   = lane & 3;                 // physical 16B slot
    const int sl0 = p ^ ((rr0 >> 1) & 3);     // logical (global) slot
    const int sl1 = p ^ ((rr1 >> 1) & 3);
    const _Float16* ga0 = A + (size_t)(m0 + rr0) * K + sl0 * 8;
    const _Float16* ga1 = A + (size_t)(m0 + rr1) * K + sl1 * 8;
    const _Float16* gb0 = W + (size_t)(n0 + rr0) * K + sl0 * 8;
    const _Float16* gb1 = W + (size_t)(n0 + rr1) * K + sl1 * 8;
    char* dA = As + w * 1024 + lane * 16;
    char* dB = Bs + w * 1024 + lane * 16;

    int offA[4], offB[4];
#pragma unroll
    for (int i = 0; i < 4; ++i) {
        const int ra = wr * 64 + i * 16 + ln;
        offA[i] = ra * 64 + ((g ^ ((ra >> 1) & 3)) << 4);
        const int rb = wc * 64 + i * 16 + ln;
        offB[i] = rb * 64 + ((g ^ ((rb >> 1) & 3)) << 4);
    }

#pragma unroll
    for (int i = 0; i < 4; ++i)
#pragma unroll
        for (int j = 0; j < 4; ++j) acc[i][j] = (f32x4){0.f, 0.f, 0.f, 0.f};

    for (int kb = 0; kb < K; kb += 32) {
        __syncthreads();
        gload_lds16(ga0 + kb, dA);
        gload_lds16(ga1 + kb, dA + 4096);
        gload_lds16(gb0 + kb, dB);
        gload_lds16(gb1 + kb, dB + 4096);
        __syncthreads();
        half8 af[4], bf[4];
#pragma unroll
        for (int i = 0; i < 4; ++i) af[i] = *(const half8*)(As + offA[i]);
#pragma unroll
        for (int j = 0; j < 4; ++j) bf[j] = *(const half8*)(Bs + offB[j]);
#pragma unroll
        for (int i = 0; i < 4; ++i)
#pragma unroll
            for (int j = 0; j < 4; ++j)
                acc[i][j] = __builtin_amdgcn_mfma_f32_16x16x32_f16(af[i], bf[j], acc[i][j], 0, 0, 0);
    }
}

// ---------------- fused QKV projection GEMM (z selects Q/K/V) ----------------
// z=0/1: write fp16 head-major [bh][s][64] (Q/K). z=2: write Vt [bh][64][2048].
__global__ __launch_bounds__(256)
void gemm_qkv(const _Float16* __restrict__ x16,
              const _Float16* __restrict__ Wq16, const _Float16* __restrict__ Wk16,
              const _Float16* __restrict__ Wv16,
              const float* __restrict__ bq, const float* __restrict__ bk,
              const float* __restrict__ bv,
              _Float16* __restrict__ Qh, _Float16* __restrict__ Kh,
              _Float16* __restrict__ Vt)
{
    __shared__ __align__(16) char As[8192];
    __shared__ __align__(16) char Bs[8192];
    const int z = blockIdx.z;
    const _Float16* W = (z == 0) ? Wq16 : (z == 1) ? Wk16 : Wv16;
    const float* bias = (z == 0) ? bq : (z == 1) ? bk : bv;
    const int m0 = blockIdx.y * 128, n0 = blockIdx.x * 128;

    f32x4 acc[4][4];
    gemm_core(x16, W, HH, m0, n0, As, Bs, acc);

    const int t = threadIdx.x;
    const int w = t >> 6, lane = t & 63;
    const int ln = lane & 15, g = lane >> 4;
    const int wr = w >> 1, wc = w & 1;
    const int mBase = m0 + wr * 64 + g * 4;
    const int nBase = n0 + wc * 64 + ln;

    if (z < 2) {
        _Float16* O = z ? Kh : Qh;
#pragma unroll
        for (int j = 0; j < 4; ++j) {
            const int n = nBase + j * 16;
            const int h = n >> 6, d = n & 63;
            const float bvf = bias[n];
#pragma unroll
            for (int i = 0; i < 4; ++i) {
                const int m = mBase + i * 16;
                const int b = m >> 11, s = m & (SS - 1);
                _Float16* dst = O + (((size_t)(b * NH + h) * SS + s) * HD + d);
#pragma unroll
                for (int r = 0; r < 4; ++r)
                    dst[(size_t)r * HD] = (_Float16)(acc[i][j][r] + bvf);
            }
        }
    } else {
#pragma unroll
        for (int j = 0; j < 4; ++j) {
            const int n = nBase + j * 16;
            const int h = n >> 6, d = n & 63;
            const float bvf = bias[n];
#pragma unroll
            for (int i = 0; i < 4; ++i) {
                const int m = mBase + i * 16;
                const int b = m >> 11, s = m & (SS - 1);
                half4v v;
#pragma unroll
                for (int r = 0; r < 4; ++r) v[r] = (_Float16)(acc[i][j][r] + bvf);
                *(half4v*)(Vt + ((size_t)(b * NH + h) * HD + d) * SS + s) = v;
            }
        }
    }
}

// ---------------- output GEMM: out[M,1024] fp32 = Ob @ Wc^T ----------------
__global__ __launch_bounds__(256)
void gemm_out(const _Float16* __restrict__ Ob, const _Float16* __restrict__ Wc16,
              float* __restrict__ C)
{
    __shared__ __align__(16) char As[8192];
    __shared__ __align__(16) char Bs[8192];
    const int m0 = blockIdx.y * 128, n0 = blockIdx.x * 128;

    f32x4 acc[4][4];
    gemm_core(Ob, Wc16, HH, m0, n0, As, Bs, acc);

    const int t = threadIdx.x;
    const int w = t >> 6, lane = t & 63;
    const int ln = lane & 15, g = lane >> 4;
    const int wr = w >> 1, wc = w & 1;
    const int mBase = m0 + wr * 64 + g * 4;
    const int nBase = n0 + wc * 64 + ln;
#pragma unroll
    for (int i = 0; i < 4; ++i)
#pragma unroll
        for (int j = 0; j < 4; ++j) {
            const int n = nBase + j * 16;
#pragma unroll
            for (int r = 0; r < 4; ++r)
                C[(size_t)(mBase + i * 16 + r) * HH + n] = acc[i][j][r];
        }
}

// ---------------- fp16-MFMA flash attention (round-1, fp16 output) ----------------
__global__ __launch_bounds__(256, 2)
void attn_mfma(const _Float16* __restrict__ Qh, const _Float16* __restrict__ Kh,
               const _Float16* __restrict__ Vt, const int* __restrict__ mk,
               _Float16* __restrict__ Ob)
{
    __shared__ __align__(16) char ksm[64 * 128];
    __shared__ __align__(16) char vsm[64 * 128];
    __shared__ float amem[64];

    const int t  = threadIdx.x;
    const int w  = t >> 6;
    const int l  = t & 63;
    const int ln = l & 15;
    const int g  = l >> 4;
    const int bh = blockIdx.y;
    const int b  = bh >> 4;
    const int h  = bh & 15;
    const int qbase = (blockIdx.x << 8) + w * 64;

    half8 qf[4][2];
    int   qm[4];
    f32x4 oacc[4][4];
    float mrun[4], lrun[4];
#pragma unroll
    for (int qs = 0; qs < 4; ++qs) {
        const int qg = qbase + qs * 16 + ln;
        const _Float16* qp = Qh + ((size_t)bh * SS + qg) * HD + g * 8;
        qf[qs][0] = *(const half8*)qp;
        qf[qs][1] = *(const half8*)(qp + 32);
        qm[qs] = mk[b * SS + qg];
        mrun[qs] = -1e30f; lrun[qs] = 0.f;
#pragma unroll
        for (int dd = 0; dd < 4; ++dd) oacc[qs][dd] = (f32x4){0.f, 0.f, 0.f, 0.f};
    }

    const int sr   = t >> 2;
    const int scb  = (t & 3) << 5;
    const int swzs = (sr & 7) << 4;

    for (int j0 = 0; j0 < SS; j0 += 64) {
        __syncthreads();
        {
            const char* kg = (const char*)(Kh + ((size_t)bh * SS + j0 + sr) * HD);
            half8 a0 = *(const half8*)(kg + scb);
            half8 a1 = *(const half8*)(kg + scb + 16);
            *(half8*)(ksm + ((sr * 128 + scb)      ^ swzs)) = a0;
            *(half8*)(ksm + ((sr * 128 + scb + 16) ^ swzs)) = a1;
            const char* vg = (const char*)(Vt + ((size_t)bh * HD + sr) * SS + j0);
            half8 b0 = *(const half8*)(vg + scb);
            half8 b1 = *(const half8*)(vg + scb + 16);
            *(half8*)(vsm + ((sr * 128 + scb)      ^ swzs)) = b0;
            *(half8*)(vsm + ((sr * 128 + scb + 16) ^ swzs)) = b1;
            if (t < 64) amem[t] = mk[b * SS + j0 + t] ? -1e30f : 0.f;
        }
        __syncthreads();

        half8 kf[4][2];
#pragma unroll
        for (int tau = 0; tau < 4; ++tau) {
            const int row = tau * 16 + ln;
            const int rsw = (row & 7) << 4;
            const int rb  = row * 128;
            kf[tau][0] = *(const half8*)(ksm + ((rb + g * 16)      ^ rsw));
            kf[tau][1] = *(const half8*)(ksm + ((rb + 64 + g * 16) ^ rsw));
        }
        f32x4 amv[4];
#pragma unroll
        for (int tau = 0; tau < 4; ++tau)
            amv[tau] = *(const f32x4*)&amem[tau * 16 + g * 4];

        half8 pf[4][2];
#pragma unroll
        for (int qs = 0; qs < 4; ++qs) {
            f32x4 sa[4];
#pragma unroll
            for (int tau = 0; tau < 4; ++tau) {
                sa[tau] = (f32x4){0.f, 0.f, 0.f, 0.f};
                sa[tau] = __builtin_amdgcn_mfma_f32_16x16x32_f16(kf[tau][0], qf[qs][0], sa[tau], 0, 0, 0);
                sa[tau] = __builtin_amdgcn_mfma_f32_16x16x32_f16(kf[tau][1], qf[qs][1], sa[tau], 0, 0, 0);
            }
            const int rel = (qbase + qs * 16 + ln) - j0;
            float sv[4][4];
#pragma unroll
            for (int tau = 0; tau < 4; ++tau)
#pragma unroll
                for (int r = 0; r < 4; ++r) {
                    float s = fmaf(sa[tau][r], 0.125f, amv[tau][r]);
                    if (tau * 16 + g * 4 + r == rel) s = -1e30f;
                    sv[tau][r] = s;
                }
            float mt = sv[0][0];
#pragma unroll
            for (int tau = 0; tau < 4; ++tau)
#pragma unroll
                for (int r = 0; r < 4; ++r) mt = fmaxf(mt, sv[tau][r]);
            mt = fmaxf(mt, __shfl_xor(mt, 16));
            mt = fmaxf(mt, __shfl_xor(mt, 32));
            const float mnew = fmaxf(mrun[qs], mt);
            const float corr = __expf(mrun[qs] - mnew);
            mrun[qs] = mnew;
            float wv[4][4], rs = 0.f;
#pragma unroll
            for (int tau = 0; tau < 4; ++tau)
#pragma unroll
                for (int r = 0; r < 4; ++r) {
                    const float e = (sv[tau][r] > -1e29f) ? __expf(sv[tau][r] - mnew) : 0.f;
                    wv[tau][r] = e; rs += e;
                }
            rs += __shfl_xor(rs, 16);
            rs += __shfl_xor(rs, 32);
            lrun[qs] = lrun[qs] * corr + rs;
#pragma unroll
            for (int dd = 0; dd < 4; ++dd) oacc[qs][dd] *= corr;
#pragma unroll
            for (int kk = 0; kk < 2; ++kk) {
                half8 pp;
                pp[0] = (_Float16)wv[2 * kk][0];     pp[1] = (_Float16)wv[2 * kk][1];
                pp[2] = (_Float16)wv[2 * kk][2];     pp[3] = (_Float16)wv[2 * kk][3];
                pp[4] = (_Float16)wv[2 * kk + 1][0]; pp[5] = (_Float16)wv[2 * kk + 1][1];
                pp[6] = (_Float16)wv[2 * kk + 1][2]; pp[7] = (_Float16)wv[2 * kk + 1][3];
                pf[qs][kk] = pp;
            }
        }

#pragma unroll
        for (int dd = 0; dd < 4; ++dd) {
            const int row = dd * 16 + ln;
            const int rsw = (row & 7) << 4;
            const int rb  = row * 128;
#pragma unroll
            for (int kk = 0; kk < 2; ++kk) {
                half4v a0 = *(const half4v*)(vsm + ((rb + kk * 64 + g * 8)      ^ rsw));
                half4v a1 = *(const half4v*)(vsm + ((rb + kk * 64 + 32 + g * 8) ^ rsw));
                half8 vf;
                vf[0] = a0[0]; vf[1] = a0[1]; vf[2] = a0[2]; vf[3] = a0[3];
                vf[4] = a1[0]; vf[5] = a1[1]; vf[6] = a1[2]; vf[7] = a1[3];
#pragma unroll
                for (int qs = 0; qs < 4; ++qs)
                    oacc[qs][dd] = __builtin_amdgcn_mfma_f32_16x16x32_f16(vf, pf[qs][kk], oacc[qs][dd], 0, 0, 0);
            }
        }
    }

#pragma unroll
    for (int qs = 0; qs < 4; ++qs) {
        const int qg = qbase + qs * 16 + ln;
        const float inv = (qm[qs] == 0 && lrun[qs] > 0.f) ? 1.f / lrun[qs] : 0.f;
        _Float16* op = Ob + ((size_t)(b * SS + qg)) * HH + h * HD + g * 4;
#pragma unroll
        for (int dd = 0; dd < 4; ++dd) {
            half4v hv;
#pragma unroll
            for (int r = 0; r < 4; ++r) hv[r] = (_Float16)(oacc[qs][dd][r] * inv);
            *(half4v*)(op + dd * 16) = hv;
        }
    }
}

// ---------------- launch ----------------
extern "C" void kernel_launch(void* const* d_in, const int* in_sizes, int n_in,
                              void* d_out, int out_size, void* d_ws, size_t ws_size,
                              hipStream_t stream)
{
    (void)in_sizes; (void)n_in; (void)out_size; (void)ws_size;

    const float* x  = (const float*)d_in[0];
    const int*   mk = (const int*)d_in[1];
    const float* Wq = (const float*)d_in[2];
    const float* bq = (const float*)d_in[3];
    const float* Wk = (const float*)d_in[4];
    const float* bk = (const float*)d_in[5];
    const float* Wv = (const float*)d_in[6];
    const float* bv = (const float*)d_in[7];
    const float* Wc = (const float*)d_in[8];
    float* out = (float*)d_out;

    const int M = BB * SS;                    // 8192
    const size_t NE = (size_t)M * HH;         // 8.39M
    const size_t NW = (size_t)HH * HH;        // 1.05M
    _Float16* x16  = (_Float16*)d_ws;
    _Float16* Wq16 = x16 + NE;
    _Float16* Wk16 = Wq16 + NW;
    _Float16* Wv16 = Wk16 + NW;
    _Float16* Wc16 = Wv16 + NW;
    _Float16* Qh   = Wc16 + NW;
    _Float16* Kh   = Qh + NE;
    _Float16* Vt   = Kh + NE;
    _Float16* Ob   = Vt + NE;

    cvt_f16<<<2048, 256, 0, stream>>>(x, x16, (int)(NE / 8));
    cvt_f16<<<512, 256, 0, stream>>>(Wq, Wq16, (int)(NW / 8));
    cvt_f16<<<512, 256, 0, stream>>>(Wk, Wk16, (int)(NW / 8));
    cvt_f16<<<512, 256, 0, stream>>>(Wv, Wv16, (int)(NW / 8));
    cvt_f16<<<512, 256, 0, stream>>>(Wc, Wc16, (int)(NW / 8));

    dim3 gq(HH / 128, M / 128, 3);            // (8, 64, 3)
    gemm_qkv<<<gq, 256, 0, stream>>>(x16, Wq16, Wk16, Wv16, bq, bk, bv, Qh, Kh, Vt);

    dim3 ga(SS / 256, BB * NH);               // (8, 64)
    attn_mfma<<<ga, 256, 0, stream>>>(Qh, Kh, Vt, mk, Ob);

    dim3 go(HH / 128, M / 128);               // (8, 64)
    gemm_out<<<go, 256, 0, stream>>>(Ob, Wc16, out);
}